// Round 3
// baseline (81.560 us; speedup 1.0000x reference)
//
#include <hip/hip_runtime.h>
#include <hip/hip_bf16.h>

// Adaptive avg pool: in (16,224,224,128) f32 NHWC -> out (16,7,7,128) f32.
// Bins are uniform 32x32 (224 = 7*32).
//
// Round-2 analysis: region-chunk blocks read 16KB islands at 112KB stride ->
// ~5.3 TB/s. Fill kernels on the same chip stream linearly at 6.8 TB/s.
// Fix: make pass-1 reads perfectly LINEAR by assigning each block whole
// H-rows (NHWC rows are contiguous; consecutive rows adjacent).
//
// Pass 1: 1792 blocks x 2 rows (224 KB linear each) = exactly 7 blocks/CU,
//   all co-resident (14 KB LDS). Row = 7168 float4; iter k: thread t reads
//   f4[k*256+t]; its j-bin is k>>2 (uniform), channel group (t%32)*4 fixed.
//   7 float4 accumulators -> shfl_xor(32) fold -> LDS (7x128 f4) -> 224 f4
//   partial per block into ws.
// Pass 2: 98 blocks; out(b,i,j,ch) = sum of 16 row-pair chunks, scale 1/1024.

#define NROWBLK 1792              // 3584 rows / 2
#define WS_F4_PER_BLK 224         // 7 j * 32 channel-groups

__global__ __launch_bounds__(256) void pool_rows(const float* __restrict__ x,
                                                 float* __restrict__ ws) {
    const int r = blockIdx.x;     // row-pair index [0,1792)
    const int t = threadIdx.x;    // [0,256)
    const int wv = t >> 6;        // wave 0..3
    const int lane = t & 63;

    const float4* base = reinterpret_cast<const float4*>(x) + (size_t)r * 2 * 7168;

    float4 acc[7];
    #pragma unroll
    for (int j = 0; j < 7; ++j) acc[j] = make_float4(0.f, 0.f, 0.f, 0.f);

    #pragma unroll
    for (int row = 0; row < 2; ++row) {
        const float4* p = base + row * 7168;
        #pragma unroll
        for (int k = 0; k < 28; ++k) {
            float4 v = p[k * 256 + t];      // fully linear, coalesced
            const int j = k >> 2;           // exact bin: (k*256+t)>>10 == k>>2
            acc[j].x += v.x; acc[j].y += v.y; acc[j].z += v.z; acc[j].w += v.w;
        }
    }

    // Fold lanes l and l^32 (same channel group, same wave).
    #pragma unroll
    for (int j = 0; j < 7; ++j) {
        acc[j].x += __shfl_xor(acc[j].x, 32);
        acc[j].y += __shfl_xor(acc[j].y, 32);
        acc[j].z += __shfl_xor(acc[j].z, 32);
        acc[j].w += __shfl_xor(acc[j].w, 32);
    }

    __shared__ float4 sm[7][128];           // [j][wave*32 + lane<32]
    if (lane < 32) {
        #pragma unroll
        for (int j = 0; j < 7; ++j) sm[j][wv * 32 + lane] = acc[j];
    }
    __syncthreads();

    if (t < WS_F4_PER_BLK) {                // t = j*32 + g
        const int j = t >> 5, g = t & 31;
        float4 s = sm[j][g];
        #pragma unroll
        for (int w = 1; w < 4; ++w) {
            float4 v = sm[j][w * 32 + g];
            s.x += v.x; s.y += v.y; s.z += v.z; s.w += v.w;
        }
        reinterpret_cast<float4*>(ws)[(size_t)r * WS_F4_PER_BLK + t] = s;
    }
}

__global__ __launch_bounds__(256) void pool_reduce_rows(const float* __restrict__ ws,
                                                        float* __restrict__ out) {
    const int e4 = blockIdx.x * 256 + threadIdx.x;  // [0, 25088) output float4s
    const int g  = e4 & 31;
    const int j  = (e4 >> 5) % 7;
    const int bi = (e4 >> 5) / 7;                   // b*7+i in [0,112)
    const float4* w4 = reinterpret_cast<const float4*>(ws);
    float4 s = make_float4(0.f, 0.f, 0.f, 0.f);
    #pragma unroll
    for (int c = 0; c < 16; ++c) {                  // 16 row-pair chunks per i-bin
        float4 v = w4[(size_t)(bi * 16 + c) * WS_F4_PER_BLK + j * 32 + g];
        s.x += v.x; s.y += v.y; s.z += v.z; s.w += v.w;
    }
    const float sc = 1.0f / 1024.0f;
    float4 o = make_float4(s.x * sc, s.y * sc, s.z * sc, s.w * sc);
    reinterpret_cast<float4*>(out)[e4] = o;         // region*32+g == e4 ordering
}

// Fallback: one block per region, no workspace.
__global__ __launch_bounds__(256) void pool_direct(const float* __restrict__ x,
                                                   float* __restrict__ out) {
    const int bid = blockIdx.x;
    const int t   = threadIdx.x;
    const int b   = bid / 49;
    const int rem = bid - b * 49;
    const int i   = rem / 7;
    const int j   = rem - i * 7;
    const size_t base_f = ((size_t)(b * 224 + i * 32) * 224 + (size_t)j * 32) * 128;
    const float4* base = reinterpret_cast<const float4*>(x + base_f);
    float4 acc = make_float4(0.f, 0.f, 0.f, 0.f);
    #pragma unroll 4
    for (int h = 0; h < 32; ++h) {
        const float4* row = base + (size_t)h * 7168;
        #pragma unroll
        for (int k = 0; k < 4; ++k) {
            float4 v = row[k * 256 + t];
            acc.x += v.x; acc.y += v.y; acc.z += v.z; acc.w += v.w;
        }
    }
    __shared__ float4 sm[256];
    sm[t] = acc;
    __syncthreads();
    if (t < 32) {
        float4 s = sm[t];
        #pragma unroll
        for (int k = 1; k < 8; ++k) {
            float4 v = sm[t + 32 * k];
            s.x += v.x; s.y += v.y; s.z += v.z; s.w += v.w;
        }
        const float sc = 1.0f / 1024.0f;
        float4 o = make_float4(s.x * sc, s.y * sc, s.z * sc, s.w * sc);
        reinterpret_cast<float4*>(out + (size_t)bid * 128)[t] = o;
    }
}

extern "C" void kernel_launch(void* const* d_in, const int* in_sizes, int n_in,
                              void* d_out, int out_size, void* d_ws, size_t ws_size,
                              hipStream_t stream) {
    const float* x = (const float*)d_in[0];
    float* out     = (float*)d_out;
    float* ws      = (float*)d_ws;

    constexpr size_t need = (size_t)NROWBLK * WS_F4_PER_BLK * sizeof(float4); // 6.4 MB
    if (ws_size >= need) {
        pool_rows<<<NROWBLK, 256, 0, stream>>>(x, ws);
        pool_reduce_rows<<<25088 / 256, 256, 0, stream>>>(ws, out);
    } else {
        pool_direct<<<16 * 7 * 7, 256, 0, stream>>>(x, out);
    }
}

// Round 4
// 68.861 us; speedup vs baseline: 1.1844x; 1.1844x over previous
//
#include <hip/hip_runtime.h>
#include <hip/hip_bf16.h>

// Adaptive avg pool: in (16,224,224,128) f32 NHWC -> out (16,7,7,128) f32.
// Bins are uniform 32x32 (224 = 7*32).
//
// Rounds 1-3: three different read structures (16KB islands / 64KB chunks /
// fully linear 224KB streams) all land at ~5.2-5.3 TB/s read, while fill
// kernels write at 6.8 TB/s. Round-4 single-variable test: NON-TEMPORAL
// loads (nt) on the streaming read -- input has zero reuse, so L2/L3
// read-allocate + eviction churn is pure overhead.
//
// Structure identical to round 3:
// Pass 1: 1792 blocks x 2 H-rows (224 KB linear) = exactly 7 blocks/CU.
//   iter k: thread t reads f4[k*256+t] (nt); j-bin = k>>2 (uniform over wave),
//   channel group (t%32)*4 fixed. 7 f4 accumulators -> shfl_xor(32) ->
//   LDS -> 224-f4 partial to ws.
// Pass 2: 98 blocks; out = sum of 16 row-pair partials, scale 1/1024.

#define NROWBLK 1792              // 3584 rows / 2
#define WS_F4_PER_BLK 224         // 7 j * 32 channel-groups

typedef float f4v __attribute__((ext_vector_type(4)));

__device__ __forceinline__ f4v nt_load4(const float4* p) {
    return __builtin_nontemporal_load(reinterpret_cast<const f4v*>(p));
}

__global__ __launch_bounds__(256) void pool_rows(const float* __restrict__ x,
                                                 float* __restrict__ ws) {
    const int r = blockIdx.x;     // row-pair index [0,1792)
    const int t = threadIdx.x;    // [0,256)
    const int wv = t >> 6;        // wave 0..3
    const int lane = t & 63;

    const float4* base = reinterpret_cast<const float4*>(x) + (size_t)r * 2 * 7168;

    f4v acc[7];
    #pragma unroll
    for (int j = 0; j < 7; ++j) acc[j] = (f4v)0.f;

    #pragma unroll
    for (int row = 0; row < 2; ++row) {
        const float4* p = base + row * 7168;
        #pragma unroll
        for (int k = 0; k < 28; ++k) {
            f4v v = nt_load4(p + k * 256 + t);  // linear, coalesced, non-temporal
            acc[k >> 2] += v;                   // exact bin: (k*256+t)>>10 == k>>2
        }
    }

    // Fold lanes l and l^32 (same channel group, same wave).
    #pragma unroll
    for (int j = 0; j < 7; ++j) {
        acc[j].x += __shfl_xor(acc[j].x, 32);
        acc[j].y += __shfl_xor(acc[j].y, 32);
        acc[j].z += __shfl_xor(acc[j].z, 32);
        acc[j].w += __shfl_xor(acc[j].w, 32);
    }

    __shared__ f4v sm[7][128];              // [j][wave*32 + lane<32]
    if (lane < 32) {
        #pragma unroll
        for (int j = 0; j < 7; ++j) sm[j][wv * 32 + lane] = acc[j];
    }
    __syncthreads();

    if (t < WS_F4_PER_BLK) {                // t = j*32 + g
        const int j = t >> 5, g = t & 31;
        f4v s = sm[j][g];
        #pragma unroll
        for (int w = 1; w < 4; ++w) s += sm[j][w * 32 + g];
        float4 o = make_float4(s.x, s.y, s.z, s.w);
        reinterpret_cast<float4*>(ws)[(size_t)r * WS_F4_PER_BLK + t] = o;
    }
}

__global__ __launch_bounds__(256) void pool_reduce_rows(const float* __restrict__ ws,
                                                        float* __restrict__ out) {
    const int e4 = blockIdx.x * 256 + threadIdx.x;  // [0, 25088) output float4s
    const int g  = e4 & 31;
    const int j  = (e4 >> 5) % 7;
    const int bi = (e4 >> 5) / 7;                   // b*7+i in [0,112)
    const float4* w4 = reinterpret_cast<const float4*>(ws);
    f4v s = (f4v)0.f;
    #pragma unroll
    for (int c = 0; c < 16; ++c)                    // 16 row-pair chunks per i-bin
        s += nt_load4(w4 + (size_t)(bi * 16 + c) * WS_F4_PER_BLK + j * 32 + g);
    s *= (1.0f / 1024.0f);
    float4 o = make_float4(s.x, s.y, s.z, s.w);
    reinterpret_cast<float4*>(out)[e4] = o;         // region*32+g == e4 ordering
}

// Fallback: one block per region, no workspace.
__global__ __launch_bounds__(256) void pool_direct(const float* __restrict__ x,
                                                   float* __restrict__ out) {
    const int bid = blockIdx.x;
    const int t   = threadIdx.x;
    const int b   = bid / 49;
    const int rem = bid - b * 49;
    const int i   = rem / 7;
    const int j   = rem - i * 7;
    const size_t base_f = ((size_t)(b * 224 + i * 32) * 224 + (size_t)j * 32) * 128;
    const float4* base = reinterpret_cast<const float4*>(x + base_f);
    f4v acc = (f4v)0.f;
    #pragma unroll 4
    for (int h = 0; h < 32; ++h) {
        const float4* row = base + (size_t)h * 7168;
        #pragma unroll
        for (int k = 0; k < 4; ++k) acc += nt_load4(row + k * 256 + t);
    }
    __shared__ f4v sm[256];
    sm[t] = acc;
    __syncthreads();
    if (t < 32) {
        f4v s = sm[t];
        #pragma unroll
        for (int k = 1; k < 8; ++k) s += sm[t + 32 * k];
        s *= (1.0f / 1024.0f);
        float4 o = make_float4(s.x, s.y, s.z, s.w);
        reinterpret_cast<float4*>(out + (size_t)bid * 128)[t] = o;
    }
}

extern "C" void kernel_launch(void* const* d_in, const int* in_sizes, int n_in,
                              void* d_out, int out_size, void* d_ws, size_t ws_size,
                              hipStream_t stream) {
    const float* x = (const float*)d_in[0];
    float* out     = (float*)d_out;
    float* ws      = (float*)d_ws;

    constexpr size_t need = (size_t)NROWBLK * WS_F4_PER_BLK * sizeof(float4); // 6.4 MB
    if (ws_size >= need) {
        pool_rows<<<NROWBLK, 256, 0, stream>>>(x, ws);
        pool_reduce_rows<<<25088 / 256, 256, 0, stream>>>(ws, out);
    } else {
        pool_direct<<<16 * 7 * 7, 256, 0, stream>>>(x, out);
    }
}